// Round 8
// baseline (159.544 us; speedup 1.0000x reference)
//
#include <hip/hip_runtime.h>

// PBKDF2 toy-HMAC, lane-parallel (u,v), round-8: L3 de-DPP'd via hoisting.
//
// State across 16 lanes (replicated in all four row-groups):
//   u[s] = byte s,  v[s] = byte 16+s   (s = lane & 15)
// absorb: u' = v + p31 ; v' = u. Gathers: Dk(w)[s] = w[(s+k)&15] (DPP row_ror).
//
// Mix round (r[i] ^= r[(i+17)%32] + r[(i+11)%32], i=0..31, masks deferred):
//  L1 (bytes 0-14):  nu1 = u ^ (D1(v) + (s<=4 ? D11(u) : D11(v)))
//  L2 (byte 15, bytes 16-29):
//      A2 = D1(nu1)   [dst14 garbage, unconsumed]
//      Bu2 = D11(nu1) [consumed dst 5..13 by L2, dst 14,15 by L3 (src 9,10 fresh)]
//      g11b = (s<=4 || s==15) ? D11(v_old) : Bu2
//      sum2 = A2 + g11b ; nu2 = u ^ sum2 ; nv2 = v ^ sum2
//      u' = (s<=14) ? nu1 : nu2
//  L3 (bytes 30,31; only dst s=14,15 consumed) -- HOISTED form:
//      need g17c[14] = nu2[15] = u[15]^sum2[15], g17c[15] = nv2[0] = v[0]^sum2[0]
//      R1(A2)  @{14,15} = {A2[15],A2[0]} = {nu1[0],nu1[1]} = D2(nu1)   (h)
//      R1(g11b)@{14,15} = {g11b[15],g11b[0]} = {v[10],v[11]} = D12(v)  (old!)
//      R1(W)   @{14,15} = {u[15],v[0]} = (s==15 ? D1(v) : D1(u))       (old!)
//      => g17c = R1W ^ (h + D12(v));  nv3 = v ^ (g17c + Bu2)
//      v' = (s<=13) ? nv2 : nv3
// Critical path/round: 2 DPP layers (start-layer; {A2,Bu2,h} on nu1) + ~8 plain
// (was 3 DPP layers + ~10 plain). 22 instrs/round.
// DPP rotate direction runtime-probed (uniform branch, zero per-iter cost).
// All &255 deferred to the end: +, ^, *31 preserve low 8 bits mod 2^32.

template<bool FLIP>
__device__ __forceinline__ void run_chain(unsigned &u, unsigned &v,
                                          unsigned &Fu, unsigned &Fv,
                                          unsigned p31v,
                                          bool m_le4, bool m_le13, bool m_le14,
                                          bool m_s15, bool m_l2)
{
    // primary semantics: row_ror:N => dst s <- src (s-N)&15
    //   D1 : dst<-src(s+1)  => N=15 -> 0x12F ; flipped -> 0x121
    //   D2 : dst<-src(s+2)  => N=14 -> 0x12E ; flipped -> 0x122
    //   D11: dst<-src(s+11) => N=5  -> 0x125 ; flipped -> 0x12B
    //   D12: dst<-src(s+12) => N=4  -> 0x124 ; flipped -> 0x12C
    constexpr int P1  = FLIP ? 0x121 : 0x12F;
    constexpr int P2  = FLIP ? 0x122 : 0x12E;
    constexpr int P11 = FLIP ? 0x12B : 0x125;
    constexpr int P12 = FLIP ? 0x12C : 0x124;

#define D1(w)  ((unsigned)__builtin_amdgcn_mov_dpp((int)(w), P1,  0xF, 0xF, false))
#define D2(w)  ((unsigned)__builtin_amdgcn_mov_dpp((int)(w), P2,  0xF, 0xF, false))
#define D11(w) ((unsigned)__builtin_amdgcn_mov_dpp((int)(w), P11, 0xF, 0xF, false))
#define D12(w) ((unsigned)__builtin_amdgcn_mov_dpp((int)(w), P12, 0xF, 0xF, false))

#define MIXROUND                                                   \
  { unsigned Bv   = D11(v);                                        \
    unsigned Bu1  = D11(u);                                        \
    unsigned A1   = D1(v);                                         \
    unsigned R1u  = D1(u);                                         \
    unsigned R12v = D12(v);                                        \
    unsigned R1W  = m_s15 ? A1 : R1u;                              \
    unsigned g11a = m_le4 ? Bu1 : Bv;                              \
    unsigned nu1  = u ^ (A1 + g11a);                               \
    unsigned A2   = D1(nu1);                                       \
    unsigned Bu2  = D11(nu1);                                      \
    unsigned h    = D2(nu1);                                       \
    unsigned g11b = m_l2 ? Bv : Bu2;                               \
    unsigned sum2 = A2 + g11b;                                     \
    unsigned nu2  = u ^ sum2;                                      \
    unsigned nv2  = v ^ sum2;                                      \
    u = m_le14 ? nu1 : nu2;                                        \
    unsigned r1s  = h + R12v;                                      \
    unsigned g17c = R1W ^ r1s;                                     \
    unsigned nv3  = v ^ (g17c + Bu2);                              \
    v = m_le13 ? nv2 : nv3;                                        \
  }

    // U0 mix (4 rounds)
    MIXROUND; MIXROUND; MIXROUND; MIXROUND;

    Fu = u; Fv = v;

    #pragma unroll 2
    for (int it = 0; it < 999; ++it) {
        // absorb: u' = v + p31 ; v' = u
        unsigned nu = v + p31v;
        v = u;
        u = nu;
        MIXROUND; MIXROUND; MIXROUND; MIXROUND;
        Fu ^= u;
        Fv ^= v;
    }

#undef MIXROUND
#undef D12
#undef D11
#undef D2
#undef D1
}

__global__ void __launch_bounds__(64) Model_62955630625117_kernel(
    const int* __restrict__ pw_g,
    const int* __restrict__ salt_g,
    int* __restrict__ out)
{
    const int lane = (int)threadIdx.x;
    const unsigned s = (unsigned)(lane & 15);

    // loop-invariant lane masks
    const bool m_le4  = (s <= 4u);
    const bool m_le13 = (s <= 13u);
    const bool m_le14 = (s <= 14u);
    const bool m_s15  = (s == 15u);
    const bool m_l2   = (s <= 4u) || (s == 15u);

    // --- probe DPP row_ror direction ---
    // primary: 0x12F => dst s <- src (s+1)&15 => lane0 receives 1
    int q = __builtin_amdgcn_mov_dpp((int)s, 0x12F, 0xF, 0xF, false);
    const bool dppflip = (__builtin_amdgcn_readfirstlane(q) != 1);

    // per-lane constants (same in every 16-lane row)
    const unsigned pwv  = (unsigned)pw_g[s];
    const unsigned p31v = pwv * 31u;

    // --- initial state: U0 absorb closed form (pw || salt || {0,0,0,1}) ---
    unsigned u = (s < 4u) ? (p31v + (s == 3u ? 1u : 0u)) : pwv;
    unsigned v = (unsigned)salt_g[s];

    unsigned Fu, Fv;
    if (dppflip) run_chain<true >(u, v, Fu, Fv, p31v, m_le4, m_le13, m_le14, m_s15, m_l2);
    else         run_chain<false>(u, v, Fu, Fv, p31v, m_le4, m_le13, m_le14, m_s15, m_l2);

    if (lane < 32) out[lane] = (int)((lane < 16 ? Fu : Fv) & 255u);
}

extern "C" void kernel_launch(void* const* d_in, const int* in_sizes, int n_in,
                              void* d_out, int out_size, void* d_ws, size_t ws_size,
                              hipStream_t stream) {
    const int* pw   = (const int*)d_in[0];
    const int* salt = (const int*)d_in[1];
    int* out = (int*)d_out;
    Model_62955630625117_kernel<<<1, 64, 0, stream>>>(pw, salt, out);
}

// Round 9
// 157.908 us; speedup vs baseline: 1.0104x; 1.0104x over previous
//
#include <hip/hip_runtime.h>

// PBKDF2 toy-HMAC, lane-parallel (u,v), round-9: pre-select-then-rotate.
// Evidence R2/R7/R8: lone-wave issue cadence ~4 cyc/instr, depth secondary
// => minimize instruction count. 18 instrs/round (was 19/22).
//
// State across 16 lanes (replicated in all four row-groups):
//   u[s] = byte s,  v[s] = byte 16+s   (s = lane & 15)
// absorb: u' = v + p31 ; v' = u (rename). Dk(w)[s] = w[(s+k)&15] (DPP row_ror).
//
// Mix round (r[i] ^= r[(i+17)%32] + r[(i+11)%32], i=0..31, masks deferred),
// 3 levels: bytes {0-14 | 15-29 | 30-31}. Verified position-by-position:
//  w1 = j>=11 ? u : v;  g11a = D11(w1)
//    [dst 0..4 <- u[s+11] (L1 +11, old); 5..14 <- v[s-5] (old); 15 <- v[10]]
//  A1 = D1(v)  [byte s+17 old]
//  nu1 = u ^ (A1 + g11a)          -- L1, valid lanes 0..14
//  A2 = D1(nu1) [dst s<-nu1[s+1]: +17 ops for bytes 16..29 (s<=13) and
//                dst15<-nu1[0] = +17 op for byte 15; dst14 garbage, unconsumed]
//  w2 = j>=11 ? v : nu1;  G = D11(w2)
//    [dst 0..4 <- v[s+11] (bytes 27..31 old, L2 +11); 5..13 <- nu1[0..8]
//     (fresh, L2 +11); 14 <- nu1[9], 15 <- nu1[10] (fresh, L3 +11)]
//  sum2 = A2 + G ; nv2 = v ^ sum2  -- L2 v-part, valid lanes 0..13
//  sumU = A2 + g11a ; nuX = u ^ sumU -- lane15: u[15]^(nu1[0]+v[10]) = byte15 L2
//  u' = (s<=14) ? nu1 : nuX
//  m = (s==15) ? nuX : nv2 ;  g17c = D1(m)
//    [dst14 <- m[15]=nuX[15]=new byte15 (L3 +17 for byte30);
//     dst15 <- m[0]=nv2[0]=new byte16 (L3 +17 for byte31)]
//  nv3 = v ^ (g17c + G)           -- L3, valid lanes 14,15
//  v' = (s<=13) ? nv2 : nv3
// DPP rotate direction runtime-probed (uniform branch, zero per-iter cost).
// All &255 deferred to the end: +, ^, *31 preserve low 8 bits mod 2^32.

template<bool FLIP>
__device__ __forceinline__ void run_chain(unsigned &u, unsigned &v,
                                          unsigned &Fu, unsigned &Fv,
                                          unsigned p31v,
                                          bool j_ge11, bool m_le13,
                                          bool m_le14, bool m_s15)
{
    // primary semantics: row_ror:N => dst s <- src (s-N)&15
    //   D1 : dst<-src(s+1)  => N=15 -> 0x12F ; flipped -> 0x121
    //   D11: dst<-src(s+11) => N=5  -> 0x125 ; flipped -> 0x12B
    constexpr int P1  = FLIP ? 0x121 : 0x12F;
    constexpr int P11 = FLIP ? 0x12B : 0x125;

#define D1(w)  ((unsigned)__builtin_amdgcn_mov_dpp((int)(w), P1,  0xF, 0xF, false))
#define D11(w) ((unsigned)__builtin_amdgcn_mov_dpp((int)(w), P11, 0xF, 0xF, false))

#define MIXROUND                                                   \
  { unsigned w1   = j_ge11 ? u : v;                                \
    unsigned g11a = D11(w1);                                       \
    unsigned A1   = D1(v);                                         \
    unsigned nu1  = u ^ (A1 + g11a);                               \
    unsigned A2   = D1(nu1);                                       \
    unsigned w2   = j_ge11 ? v : nu1;                              \
    unsigned G    = D11(w2);                                       \
    unsigned sum2 = A2 + G;                                        \
    unsigned nv2  = v ^ sum2;                                      \
    unsigned sumU = A2 + g11a;                                     \
    unsigned nuX  = u ^ sumU;                                      \
    u = m_le14 ? nu1 : nuX;                                        \
    unsigned m_   = m_s15 ? nuX : nv2;                             \
    unsigned g17c = D1(m_);                                        \
    unsigned nv3  = v ^ (g17c + G);                                \
    v = m_le13 ? nv2 : nv3;                                        \
  }

    // U0 mix (4 rounds)
    MIXROUND; MIXROUND; MIXROUND; MIXROUND;

    Fu = u; Fv = v;

    #pragma unroll 4
    for (int it = 0; it < 999; ++it) {
        // absorb: u' = v + p31 ; v' = u (rename)
        unsigned nu = v + p31v;
        v = u;
        u = nu;
        MIXROUND; MIXROUND; MIXROUND; MIXROUND;
        Fu ^= u;
        Fv ^= v;
    }

#undef MIXROUND
#undef D11
#undef D1
}

__global__ void __launch_bounds__(64) Model_62955630625117_kernel(
    const int* __restrict__ pw_g,
    const int* __restrict__ salt_g,
    int* __restrict__ out)
{
    const int lane = (int)threadIdx.x;
    const unsigned s = (unsigned)(lane & 15);

    // loop-invariant lane masks
    const bool j_ge11 = (s >= 11u);
    const bool m_le13 = (s <= 13u);
    const bool m_le14 = (s <= 14u);
    const bool m_s15  = (s == 15u);

    // --- probe DPP row_ror direction ---
    // primary: 0x12F => dst s <- src (s+1)&15 => lane0 receives 1
    int q = __builtin_amdgcn_mov_dpp((int)s, 0x12F, 0xF, 0xF, false);
    const bool dppflip = (__builtin_amdgcn_readfirstlane(q) != 1);

    // per-lane constants (same in every 16-lane row)
    const unsigned pwv  = (unsigned)pw_g[s];
    const unsigned p31v = pwv * 31u;

    // --- initial state: U0 absorb closed form (pw || salt || {0,0,0,1}) ---
    unsigned u = (s < 4u) ? (p31v + (s == 3u ? 1u : 0u)) : pwv;
    unsigned v = (unsigned)salt_g[s];

    unsigned Fu, Fv;
    if (dppflip) run_chain<true >(u, v, Fu, Fv, p31v, j_ge11, m_le13, m_le14, m_s15);
    else         run_chain<false>(u, v, Fu, Fv, p31v, j_ge11, m_le13, m_le14, m_s15);

    if (lane < 32) out[lane] = (int)((lane < 16 ? Fu : Fv) & 255u);
}

extern "C" void kernel_launch(void* const* d_in, const int* in_sizes, int n_in,
                              void* d_out, int out_size, void* d_ws, size_t ws_size,
                              hipStream_t stream) {
    const int* pw   = (const int*)d_in[0];
    const int* salt = (const int*)d_in[1];
    int* out = (int*)d_out;
    Model_62955630625117_kernel<<<1, 64, 0, stream>>>(pw, salt, out);
}

// Round 10
// 152.717 us; speedup vs baseline: 1.0447x; 1.0340x over previous
//
#include <hip/hip_runtime.h>

// PBKDF2 toy-HMAC, lane-parallel (u,v), round-10: hazard-spaced schedule.
//
// Model (R7/R8/R9 triangulation): lone-wave issue = 4 cyc/instr on ANY pipe;
// a DPP consuming a value written by the IMMEDIATELY preceding instruction
// costs ~+1 extra slot (hazard s_nops, inserted post-RA; the scheduler does
// not hide them). R9 = 75 instrs but +19 hazard slots = 376 cyc/iter.
// This round keeps R9's exact 18-instr dataflow (PASSED, absmax=0) and pins
// an order via sched_barrier(0) so every DPP source is >=2 slots old:
//   w1 | A1 | g11a(w1@-2) | nu1 | w2 | A2(nu1@-2) | G(w2@-2) |
//   nv2,nuX | m_ | u-merge | g17c(m_@-2) | nv3, v-merge
// Round boundary: ... v-merge | w1 | A1(v@-2) -- spaced. Iter boundary has
// F-xors + absorb for extra slack. Predicted ~304 cyc/iter ~= 127 us.
//
// State across 16 lanes (replicated in all four row-groups):
//   u[s] = byte s,  v[s] = byte 16+s   (s = lane & 15)
// absorb: u' = v + p31 ; v' = u (rename). Dk(w)[s] = w[(s+k)&15] (DPP row_ror).
// Mix round (r[i] ^= r[(i+17)%32] + r[(i+11)%32], i=0..31, masks deferred),
// 3 levels {0-14 | 15-29 | 30-31}; equations identical to round-9 (verified
// position-by-position there). All &255 deferred to the end.

template<bool FLIP>
__device__ __forceinline__ void run_chain(unsigned &u, unsigned &v,
                                          unsigned &Fu, unsigned &Fv,
                                          unsigned p31v,
                                          bool j_ge11, bool m_le13,
                                          bool m_le14, bool m_s15)
{
    // primary semantics: row_ror:N => dst s <- src (s-N)&15
    //   D1 : dst<-src(s+1)  => N=15 -> 0x12F ; flipped -> 0x121
    //   D11: dst<-src(s+11) => N=5  -> 0x125 ; flipped -> 0x12B
    constexpr int P1  = FLIP ? 0x121 : 0x12F;
    constexpr int P11 = FLIP ? 0x12B : 0x125;

#define D1(w)  ((unsigned)__builtin_amdgcn_mov_dpp((int)(w), P1,  0xF, 0xF, false))
#define D11(w) ((unsigned)__builtin_amdgcn_mov_dpp((int)(w), P11, 0xF, 0xF, false))
#define SB()   __builtin_amdgcn_sched_barrier(0)

#define MIXROUND                                                   \
  { unsigned w1   = j_ge11 ? u : v;          SB();                 \
    unsigned A1   = D1(v);                   SB();                 \
    unsigned g11a = D11(w1);                 SB();                 \
    unsigned nu1  = u ^ (A1 + g11a);         SB();                 \
    unsigned w2   = j_ge11 ? v : nu1;        SB();                 \
    unsigned A2   = D1(nu1);                 SB();                 \
    unsigned G    = D11(w2);                 SB();                 \
    unsigned nv2  = v ^ (A2 + G);                                  \
    unsigned nuX  = u ^ (A2 + g11a);         SB();                 \
    unsigned m_   = m_s15 ? nuX : nv2;       SB();                 \
    u = m_le14 ? nu1 : nuX;                  SB();                 \
    unsigned g17c = D1(m_);                  SB();                 \
    unsigned nv3  = v ^ (g17c + G);                                \
    v = m_le13 ? nv2 : nv3;                  SB();                 \
  }

    // U0 mix (4 rounds)
    MIXROUND; MIXROUND; MIXROUND; MIXROUND;

    Fu = u; Fv = v;

    #pragma unroll 4
    for (int it = 0; it < 999; ++it) {
        // absorb: u' = v + p31 ; v' = u (rename)
        unsigned nu = v + p31v;
        v = u;
        u = nu;
        SB();
        MIXROUND; MIXROUND; MIXROUND; MIXROUND;
        Fu ^= u;
        Fv ^= v;
        SB();
    }

#undef MIXROUND
#undef SB
#undef D11
#undef D1
}

__global__ void __launch_bounds__(64) Model_62955630625117_kernel(
    const int* __restrict__ pw_g,
    const int* __restrict__ salt_g,
    int* __restrict__ out)
{
    const int lane = (int)threadIdx.x;
    const unsigned s = (unsigned)(lane & 15);

    // loop-invariant lane masks
    const bool j_ge11 = (s >= 11u);
    const bool m_le13 = (s <= 13u);
    const bool m_le14 = (s <= 14u);
    const bool m_s15  = (s == 15u);

    // --- probe DPP row_ror direction ---
    // primary: 0x12F => dst s <- src (s+1)&15 => lane0 receives 1
    int q = __builtin_amdgcn_mov_dpp((int)s, 0x12F, 0xF, 0xF, false);
    const bool dppflip = (__builtin_amdgcn_readfirstlane(q) != 1);

    // per-lane constants (same in every 16-lane row)
    const unsigned pwv  = (unsigned)pw_g[s];
    const unsigned p31v = pwv * 31u;

    // --- initial state: U0 absorb closed form (pw || salt || {0,0,0,1}) ---
    unsigned u = (s < 4u) ? (p31v + (s == 3u ? 1u : 0u)) : pwv;
    unsigned v = (unsigned)salt_g[s];

    unsigned Fu, Fv;
    if (dppflip) run_chain<true >(u, v, Fu, Fv, p31v, j_ge11, m_le13, m_le14, m_s15);
    else         run_chain<false>(u, v, Fu, Fv, p31v, j_ge11, m_le13, m_le14, m_s15);

    if (lane < 32) out[lane] = (int)((lane < 16 ? Fu : Fv) & 255u);
}

extern "C" void kernel_launch(void* const* d_in, const int* in_sizes, int n_in,
                              void* d_out, int out_size, void* d_ws, size_t ws_size,
                              hipStream_t stream) {
    const int* pw   = (const int*)d_in[0];
    const int* salt = (const int*)d_in[1];
    int* out = (int*)d_out;
    Model_62955630625117_kernel<<<1, 64, 0, stream>>>(pw, salt, out);
}

// Round 11
// 144.517 us; speedup vs baseline: 1.1040x; 1.0567x over previous
//
#include <hip/hip_runtime.h>

// PBKDF2 toy-HMAC, lane-parallel (u,v), round-11: 17-instr round (w3/m_ trick)
// + R10's DPP @-2 hazard spacing (sched_barrier-pinned).
//
// Model: lone-wave issue ~4.75 cyc/instr with @-2-spaced DPP (R10: 361 cyc /
// 76 instrs). Minimize instrs, keep spacing.
//
// State across 16 lanes (replicated in all four row-groups):
//   u[s] = byte s,  v[s] = byte 16+s   (s = lane & 15)
// absorb: u' = v + p31 ; v' = u (rename). Dk(w)[s] = w[(s+k)&15] (DPP row_ror).
//
// Mix round (r[i] ^= r[(i+17)%32] + r[(i+11)%32], i=0..31, masks deferred),
// 3 levels {0-14 | 15-29 | 30-31}. Position-verified equations:
//  w1 = j>=11 ? u : v ; w3 = s==15 ? u : v          (old, off-path)
//  A1 = D1(v)          [+17 ops for bytes 0..14: old v[s+1] = byte 17+s]
//  g11a = D11(w1)      [dst 0..4 <- u[s+11]; 5..14 <- v[s-5]; 15 <- v[10]]
//  nu1 = u ^ (A1 + g11a)      -- L1 valid 0..14 (nu1[15] garbage)
//  w2 = j>=11 ? v : nu1
//  A2 = D1(nu1)        [dst s<=13 <- nu1[s+1] fresh (+17 for byte 16+s);
//                       dst15 <- nu1[0] fresh (+17 for byte 15); dst14 garbage]
//  G  = D11(w2)        [dst 0..4 <- v[s+11] old (+11 for byte 16+s);
//                       5..13 <- nu1[s-5] fresh; 14,15 <- nu1[9],nu1[10] fresh (L3)]
//  Gm = s==15 ? g11a : G      [lane15: v[10] = +11 op for byte 15]
//  sum = A2 + Gm
//  m_  = w3 ^ sum      [lanes 0..13: v^sum = NEW bytes 16..29 (nv2);
//                       lane 15: u^sum = NEW byte 15 (nuX); lane14 garbage]
//  u' = s<=14 ? nu1 : m_
//  g17c = D1(m_)       [dst14 <- m_[15] = new byte15 (+17 for byte 30);
//                       dst15 <- m_[0]  = new byte16 (+17 for byte 31)]
//  nv3 = v ^ (g17c + G)       -- L3 valid 14,15
//  v' = s<=13 ? m_ : nv3
// Garbage audit: m_[14] -> only g17c[13] -> nv3[13], never selected (le13
// takes m_) ; nu1[15] -> only A2[14] -> sum[14] -> m_[14] (above).
// DPP rotate direction runtime-probed. All &255 deferred to the end.

template<bool FLIP>
__device__ __forceinline__ void run_chain(unsigned &u, unsigned &v,
                                          unsigned &Fu, unsigned &Fv,
                                          unsigned p31v,
                                          bool j_ge11, bool m_le13,
                                          bool m_le14, bool m_s15)
{
    // primary semantics: row_ror:N => dst s <- src (s-N)&15
    //   D1 : dst<-src(s+1)  => N=15 -> 0x12F ; flipped -> 0x121
    //   D11: dst<-src(s+11) => N=5  -> 0x125 ; flipped -> 0x12B
    constexpr int P1  = FLIP ? 0x121 : 0x12F;
    constexpr int P11 = FLIP ? 0x12B : 0x125;

#define D1(w)  ((unsigned)__builtin_amdgcn_mov_dpp((int)(w), P1,  0xF, 0xF, false))
#define D11(w) ((unsigned)__builtin_amdgcn_mov_dpp((int)(w), P11, 0xF, 0xF, false))
#define SB()   __builtin_amdgcn_sched_barrier(0)

#define MIXROUND                                                   \
  { unsigned w1   = j_ge11 ? u : v;          SB();                 \
    unsigned w3   = m_s15 ? u : v;           SB();                 \
    unsigned A1   = D1(v);                   SB();                 \
    unsigned g11a = D11(w1);                 SB();                 \
    unsigned nu1  = u ^ (A1 + g11a);         SB();                 \
    unsigned w2   = j_ge11 ? v : nu1;        SB();                 \
    unsigned A2   = D1(nu1);                 SB();                 \
    unsigned G    = D11(w2);                 SB();                 \
    unsigned Gm   = m_s15 ? g11a : G;        SB();                 \
    unsigned m_   = w3 ^ (A2 + Gm);          SB();                 \
    u = m_le14 ? nu1 : m_;                   SB();                 \
    unsigned g17c = D1(m_);                  SB();                 \
    unsigned nv3  = v ^ (g17c + G);                                \
    v = m_le13 ? m_ : nv3;                   SB();                 \
  }

    // U0 mix (4 rounds)
    MIXROUND; MIXROUND; MIXROUND; MIXROUND;

    Fu = u; Fv = v;

    #pragma unroll 3
    for (int it = 0; it < 999; ++it) {
        // absorb: u' = v + p31 ; v' = u (rename)
        unsigned nu = v + p31v;
        v = u;
        u = nu;
        SB();
        MIXROUND; MIXROUND; MIXROUND; MIXROUND;
        Fu ^= u;
        Fv ^= v;
        SB();
    }

#undef MIXROUND
#undef SB
#undef D11
#undef D1
}

__global__ void __launch_bounds__(64) Model_62955630625117_kernel(
    const int* __restrict__ pw_g,
    const int* __restrict__ salt_g,
    int* __restrict__ out)
{
    const int lane = (int)threadIdx.x;
    const unsigned s = (unsigned)(lane & 15);

    // loop-invariant lane masks
    const bool j_ge11 = (s >= 11u);
    const bool m_le13 = (s <= 13u);
    const bool m_le14 = (s <= 14u);
    const bool m_s15  = (s == 15u);

    // --- probe DPP row_ror direction ---
    // primary: 0x12F => dst s <- src (s+1)&15 => lane0 receives 1
    int q = __builtin_amdgcn_mov_dpp((int)s, 0x12F, 0xF, 0xF, false);
    const bool dppflip = (__builtin_amdgcn_readfirstlane(q) != 1);

    // per-lane constants (same in every 16-lane row)
    const unsigned pwv  = (unsigned)pw_g[s];
    const unsigned p31v = pwv * 31u;

    // --- initial state: U0 absorb closed form (pw || salt || {0,0,0,1}) ---
    unsigned u = (s < 4u) ? (p31v + (s == 3u ? 1u : 0u)) : pwv;
    unsigned v = (unsigned)salt_g[s];

    unsigned Fu, Fv;
    if (dppflip) run_chain<true >(u, v, Fu, Fv, p31v, j_ge11, m_le13, m_le14, m_s15);
    else         run_chain<false>(u, v, Fu, Fv, p31v, j_ge11, m_le13, m_le14, m_s15);

    if (lane < 32) out[lane] = (int)((lane < 16 ? Fu : Fv) & 255u);
}

extern "C" void kernel_launch(void* const* d_in, const int* in_sizes, int n_in,
                              void* d_out, int out_size, void* d_ws, size_t ws_size,
                              hipStream_t stream) {
    const int* pw   = (const int*)d_in[0];
    const int* salt = (const int*)d_in[1];
    int* out = (int*)d_out;
    Model_62955630625117_kernel<<<1, 64, 0, stream>>>(pw, salt, out);
}

// Round 12
// 142.501 us; speedup vs baseline: 1.1196x; 1.0142x over previous
//
#include <hip/hip_runtime.h>

// PBKDF2 toy-HMAC, lane-parallel (u,v), round-12: s_nop sharing + F-xor gap fill.
//
// Microarch model (R10/R11 calibrated): lone-wave issue = 1 instr / 4 cyc; the
// post-RA hazard recognizer inserts 1 s_nop per DPP whose source is 2 instrs
// back (@-2); @-3 is free. Each s_nop burns a 4-cyc slot.
// R11 = 17 instrs + 3 nops = 20 slots/round (measured 84.5/iter).
// This round: (a) order nu1,w2,A2,G so ONE nop serves both A2 and G hazards;
// same for m_,umerge,g17c -> 2 nops/round. (b) round 1 of each iteration
// carries the two F-accumulation xors in exactly those gap positions (their
// operands oldu/oldv are far back -> legal fillers, no nops in round 1).
// F re-based: Fu=Fv=0; iter k's round-1 xors accumulate U_k; epilogue xors
// U_999. Total = U0^U1^...^U999 (= 1000 terms) as required.
// Expected ~77.5 slots/iter = 310 cyc -> ~129 us.
//
// State across 16 lanes (replicated in all four row-groups):
//   u[s] = byte s,  v[s] = byte 16+s   (s = lane & 15)
// absorb: u' = v + p31 ; v' = u (rename). Dk(w)[s] = w[(s+k)&15] (DPP row_ror).
// Mix round equations identical to round-11 (position-verified there; PASSED):
//   w1 = j>=11 ? u : v ; w3 = s==15 ? u : v
//   g11a = D11(w1) ; A1 = D1(v) ; nu1 = u ^ (A1 + g11a)       [L1: bytes 0-14]
//   w2 = j>=11 ? v : nu1 ; A2 = D1(nu1) ; G = D11(w2)
//   Gm = s==15 ? g11a : G ; m_ = w3 ^ (A2 + Gm)    [L2: byte15 @15, 16-29 @0-13]
//   u' = s<=14 ? nu1 : m_
//   g17c = D1(m_) ; nv3 = v ^ (g17c + G)           [L3: bytes 30,31 @ 14,15]
//   v' = s<=13 ? m_ : nv3
// DPP rotate direction runtime-probed. All &255 deferred to the end.

template<bool FLIP>
__device__ __forceinline__ void run_chain(unsigned &u, unsigned &v,
                                          unsigned &Fu, unsigned &Fv,
                                          unsigned p31v,
                                          bool j_ge11, bool m_le13,
                                          bool m_le14, bool m_s15)
{
    // primary semantics: row_ror:N => dst s <- src (s-N)&15
    //   D1 : dst<-src(s+1)  => N=15 -> 0x12F ; flipped -> 0x121
    //   D11: dst<-src(s+11) => N=5  -> 0x125 ; flipped -> 0x12B
    constexpr int P1  = FLIP ? 0x121 : 0x12F;
    constexpr int P11 = FLIP ? 0x12B : 0x125;

#define D1(w)  ((unsigned)__builtin_amdgcn_mov_dpp((int)(w), P1,  0xF, 0xF, false))
#define D11(w) ((unsigned)__builtin_amdgcn_mov_dpp((int)(w), P11, 0xF, 0xF, false))
#define SB()   __builtin_amdgcn_sched_barrier(0)

// F1/F2 are gap fillers: round 1 of each iteration passes the F-xors here;
// plain rounds pass nothing (compiler inserts the shared s_nop instead).
#define MIXROUND(F1, F2)                                           \
  { unsigned w1   = j_ge11 ? u : v;          SB();                 \
    unsigned w3   = m_s15 ? u : v;           SB();                 \
    unsigned A1   = D1(v);                   SB();                 \
    unsigned g11a = D11(w1);                 SB();                 \
    unsigned t1   = A1 + g11a;               SB();                 \
    unsigned nu1  = u ^ t1;                  SB();                 \
    unsigned w2   = j_ge11 ? v : nu1;        SB();                 \
    F1;                                      SB();                 \
    unsigned A2   = D1(nu1);                 SB();                 \
    unsigned G    = D11(w2);                 SB();                 \
    unsigned Gm   = m_s15 ? g11a : G;        SB();                 \
    unsigned t2   = A2 + Gm;                 SB();                 \
    unsigned m_   = w3 ^ t2;                 SB();                 \
    u = m_le14 ? nu1 : m_;                   SB();                 \
    F2;                                      SB();                 \
    unsigned g17c = D1(m_);                  SB();                 \
    unsigned t3   = g17c + G;                SB();                 \
    unsigned nv3  = v ^ t3;                  SB();                 \
    v = m_le13 ? m_ : nv3;                   SB();                 \
  }

#define NOP ((void)0)

    // U0 mix (4 rounds; U0 absorb done by caller closed-form)
    MIXROUND(NOP, NOP); MIXROUND(NOP, NOP);
    MIXROUND(NOP, NOP); MIXROUND(NOP, NOP);

    // F re-based at zero; iter k's round-1 gaps accumulate U_k; epilogue U_999.
    Fu = 0u; Fv = 0u;

    #pragma unroll 3
    for (int it = 0; it < 999; ++it) {
        unsigned oldu = u, oldv = v;
        u = oldv + p31v;   // absorb add
        v = oldu;          // rename
        SB();
        MIXROUND(Fu ^= oldu, Fv ^= oldv);   // gaps carry F ^= U_k
        MIXROUND(NOP, NOP);
        MIXROUND(NOP, NOP);
        MIXROUND(NOP, NOP);
    }
    // final term U_999
    Fu ^= u;
    Fv ^= v;

#undef NOP
#undef MIXROUND
#undef SB
#undef D11
#undef D1
}

__global__ void __launch_bounds__(64) Model_62955630625117_kernel(
    const int* __restrict__ pw_g,
    const int* __restrict__ salt_g,
    int* __restrict__ out)
{
    const int lane = (int)threadIdx.x;
    const unsigned s = (unsigned)(lane & 15);

    // loop-invariant lane masks
    const bool j_ge11 = (s >= 11u);
    const bool m_le13 = (s <= 13u);
    const bool m_le14 = (s <= 14u);
    const bool m_s15  = (s == 15u);

    // --- probe DPP row_ror direction ---
    // primary: 0x12F => dst s <- src (s+1)&15 => lane0 receives 1
    int q = __builtin_amdgcn_mov_dpp((int)s, 0x12F, 0xF, 0xF, false);
    const bool dppflip = (__builtin_amdgcn_readfirstlane(q) != 1);

    // per-lane constants (same in every 16-lane row)
    const unsigned pwv  = (unsigned)pw_g[s];
    const unsigned p31v = pwv * 31u;

    // --- initial state: U0 absorb closed form (pw || salt || {0,0,0,1}) ---
    unsigned u = (s < 4u) ? (p31v + (s == 3u ? 1u : 0u)) : pwv;
    unsigned v = (unsigned)salt_g[s];

    unsigned Fu, Fv;
    if (dppflip) run_chain<true >(u, v, Fu, Fv, p31v, j_ge11, m_le13, m_le14, m_s15);
    else         run_chain<false>(u, v, Fu, Fv, p31v, j_ge11, m_le13, m_le14, m_s15);

    if (lane < 32) out[lane] = (int)((lane < 16 ? Fu : Fv) & 255u);
}

extern "C" void kernel_launch(void* const* d_in, const int* in_sizes, int n_in,
                              void* d_out, int out_size, void* d_ws, size_t ws_size,
                              hipStream_t stream) {
    const int* pw   = (const int*)d_in[0];
    const int* salt = (const int*)d_in[1];
    int* out = (int*)d_out;
    Model_62955630625117_kernel<<<1, 64, 0, stream>>>(pw, salt, out);
}